// Round 8
// baseline (538.929 us; speedup 1.0000x reference)
//
#include <hip/hip_runtime.h>
#include <hip/hip_bf16.h>

// Attention_aux: fused aux-attention scorer + context + output projection.
//   1. convw1:   W1[:, :3072] -> bf16 (ws)
//   2. hbias:    hb[b,d] = hs[b,:]·W1[d,3072:] + b1[d]  (fp32)
//   3. gemm_score: bf16 MFMA  pre = enc·W1a^T ; epilogue p = sum tanh(pre+hb)*w2
//      BM=256 BN=128 BK=64, 8 waves (4Mx2N, wave 64x64, acc 4x4), 2 phases
//      per K-tile (16 MFMA each). BOTH operands via global_load_lds — A staged
//      as RAW FP32 into LDS (no reg-staging, no ds_write), converted to bf16
//      in-consumer via v_cvt_pk_bf16_f32 (VALU pipe, hidden under MFMA).
//      All LDS rows are 128 B with 8-slot XOR swizzle (R5/R6-verified 0-conflict
//      pattern, rule 21 both-sides). Counted vmcnt(8) once per tile (T4),
//      deep A prefetch (4-phase window), raw barriers, setprio (T5).
//      LDS = 128 KB A (2 dbuf x 2 kh-planes) + 32 KB B = 160 KB, 1 block/CU.
//   4. softmax over S -> alpha
//   5. ctxpart/ctxreduce: context = alpha^T · enc  (fp32, deterministic)
//   6. final:    out = context·W3^T + b3

typedef float          fx4 __attribute__((ext_vector_type(4)));
typedef short          sv8 __attribute__((ext_vector_type(8)));
typedef unsigned short uv4 __attribute__((ext_vector_type(4)));
typedef unsigned int   ui4 __attribute__((ext_vector_type(4)));

__device__ __forceinline__ unsigned short f2bf(float x) {
  unsigned u = __float_as_uint(x);
  return (unsigned short)((u + 0x7FFFu + ((u >> 16) & 1u)) >> 16);
}

// packed RNE f32x2 -> bf16x2 via HW instruction
__device__ __forceinline__ unsigned cvtpk(float lo, float hi) {
  unsigned r;
  asm("v_cvt_pk_bf16_f32 %0, %1, %2" : "=v"(r) : "v"(lo), "v"(hi));
  return r;
}
__device__ __forceinline__ sv8 pack8s(fx4 a, fx4 b) {
  ui4 v;
  v[0] = cvtpk(a[0], a[1]); v[1] = cvtpk(a[2], a[3]);
  v[2] = cvtpk(b[0], b[1]); v[3] = cvtpk(b[2], b[3]);
  sv8 r; __builtin_memcpy(&r, &v, 16); return r;
}

// ---------------- kernel 1: convert W1[:, :3072] to bf16 ----------------
__global__ void convw1_kernel(const float* __restrict__ W1, unsigned short* __restrict__ W1a) {
  int id = blockIdx.x * 256 + threadIdx.x;      // float4 id, 1024*768 total
  int d = id / 768, fi = id - d * 768;
  fx4 v = ((const fx4*)W1)[d * 1024 + fi];
  uv4 r; r[0] = f2bf(v[0]); r[1] = f2bf(v[1]); r[2] = f2bf(v[2]); r[3] = f2bf(v[3]);
  ((uv4*)W1a)[d * 768 + fi] = r;
}

// ---------------- kernel 2: hidden-state bias  hb[b,d] ----------------
__global__ void hbias_kernel(const float* __restrict__ hs, const float* __restrict__ W1,
                             const float* __restrict__ b1, float* __restrict__ hb) {
  int idx = (blockIdx.x << 2) + (threadIdx.x >> 6);   // 0..32767 = b*1024+d
  int lane = threadIdx.x & 63;
  int b = idx >> 10, d = idx & 1023;
  const fx4* hv = (const fx4*)hs;
  const fx4* wv = (const fx4*)W1;
  float s = 0.f;
#pragma unroll
  for (int i = 0; i < 4; ++i) {
    int k4 = lane + (i << 6);
    fx4 h = hv[(b << 8) + k4];
    fx4 w = wv[d * 1024 + 768 + k4];
    s += h[0] * w[0] + h[1] * w[1] + h[2] * w[2] + h[3] * w[3];
  }
#pragma unroll
  for (int off = 32; off; off >>= 1) s += __shfl_xor(s, off);
  if (lane == 0) hb[idx] = s + b1[d];
}

// ---------------- kernel 3: big GEMM + tanh·w2 epilogue ----------------
// M=32768, N=1024, K=3072. 48 K-tiles. Per phase: {ds_read frags (+cvt for A),
// issue gload_lds, barrier, lgkm0, setprio, 16 MFMA, setprio, [vmcnt], barrier}.
// Staging plan (tile j -> buf j&1):  B(j+1) issued at j P1 (L2-resident);
// A(j+2) kh0+kh1 issued at j P2 after B1 (regions freed by j P1-bar / j P2-B1).
// vmcnt(8) at j P2 retires tile j+1's 10 ops, leaves A(j+2)'s 8 in flight.
__global__ __launch_bounds__(512, 2)
void gemm_score(const float* __restrict__ enc,
                const unsigned short* __restrict__ W1a,
                const float* __restrict__ hb,
                const float* __restrict__ w2,
                float* __restrict__ pe) {
  __shared__ __align__(16) float As[2][2][8192];         // [dbuf][kh][256r x 32f] = 128 KB
  __shared__ __align__(16) unsigned short Bs[2][8192];   // [dbuf][128c x 64k]     = 32 KB

  const int t = threadIdx.x;
  const int lane = t & 63, wid = t >> 6;
  const int wm = wid >> 1, wn = wid & 1;    // 4M x 2N wave grid

  // XCD-bijective swizzle: 1024 blocks (%8==0), XCD x owns lg [x*128,+128)
  const int bid = blockIdx.x;
  const int lg = ((bid & 7) << 7) | (bid >> 3);
  const int mt = lg >> 3, ntile = lg & 7;
  const int row0 = mt << 8;            // 256-row M tile
  const int col0 = ntile << 7;         // 128-col N tile

  // ---- staging source pointers (per-lane pre-swizzled, rule 21) ----
  const int l3 = lane >> 3, l7 = lane & 7;
  const float* aptr = enc + (size_t)(row0 + wid * 32 + l3) * 3072 + ((l7 ^ l3) << 2);
  const unsigned short* bptr = W1a + (size_t)(col0 + wid * 16 + l3) * 3072 + ((l7 ^ l3) << 3);

  // ---- fragment read constants (8-slot XOR swizzle on 128 B rows) ----
  const int r15 = lane & 15, qv = lane >> 4, r7s = r15 & 7;
  const int aro = (wm * 64 + r15) * 32;          // + mi*512 ; float units
  const int sA0 = ((2 * qv) ^ r7s) << 2;
  const int sA1 = ((2 * qv + 1) ^ r7s) << 2;
  const int bco = (wn * 64 + r15) * 64;          // + ni*1024 ; ushort units
  const int sB0 = (qv ^ r7s) << 3;               // kh0 slots
  const int sB1 = ((qv + 4) ^ r7s) << 3;         // kh1 slots

  fx4 acc[4][4] = {};

#define A_ISSUE(buf, kh, kt)                                          \
  { _Pragma("unroll")                                                 \
    for (int i = 0; i < 4; ++i)                                       \
      __builtin_amdgcn_global_load_lds(                               \
        (const __attribute__((address_space(1))) void*)(aptr + i * 24576 + (kt) * 64 + (kh) * 32), \
        (__attribute__((address_space(3))) void*)&As[buf][kh][(wid * 32 + i * 8) * 32], 16, 0, 0); }
#define B_ISSUE(buf, kt)                                              \
  { _Pragma("unroll")                                                 \
    for (int i = 0; i < 2; ++i)                                       \
      __builtin_amdgcn_global_load_lds(                               \
        (const __attribute__((address_space(1))) void*)(bptr + i * 24576 + (kt) * 64), \
        (__attribute__((address_space(3))) void*)&Bs[buf][(wid * 16 + i * 8) * 64], 16, 0, 0); }
#define MFMA16                                                        \
  __builtin_amdgcn_s_setprio(1);                                      \
  { _Pragma("unroll")                                                 \
    for (int mi = 0; mi < 4; ++mi)                                    \
      _Pragma("unroll")                                               \
      for (int ni = 0; ni < 4; ++ni)                                  \
        acc[mi][ni] = __builtin_amdgcn_mfma_f32_16x16x32_bf16(af[mi], bfv[ni], acc[mi][ni], 0, 0, 0); } \
  __builtin_amdgcn_s_setprio(0);

#define PH1(kt, bp)                                                   \
  { sv8 af[4], bfv[4];                                                \
    _Pragma("unroll")                                                 \
    for (int mi = 0; mi < 4; ++mi) {                                  \
      fx4 x = *(const fx4*)&As[bp][0][aro + mi * 512 + sA0];          \
      fx4 y = *(const fx4*)&As[bp][0][aro + mi * 512 + sA1];          \
      af[mi] = pack8s(x, y);                                          \
    }                                                                 \
    _Pragma("unroll")                                                 \
    for (int ni = 0; ni < 4; ++ni)                                    \
      bfv[ni] = *(const sv8*)&Bs[bp][bco + ni * 1024 + sB0];          \
    if ((kt) < 47) { B_ISSUE((bp) ^ 1, (kt) + 1) }                    \
    __builtin_amdgcn_s_barrier();                                     \
    asm volatile("s_waitcnt lgkmcnt(0)" ::: "memory");                \
    MFMA16                                                            \
    __builtin_amdgcn_s_barrier(); }

#define PH2(kt, bp)                                                   \
  { sv8 af[4], bfv[4];                                                \
    _Pragma("unroll")                                                 \
    for (int mi = 0; mi < 4; ++mi) {                                  \
      fx4 x = *(const fx4*)&As[bp][1][aro + mi * 512 + sA0];          \
      fx4 y = *(const fx4*)&As[bp][1][aro + mi * 512 + sA1];          \
      af[mi] = pack8s(x, y);                                          \
    }                                                                 \
    _Pragma("unroll")                                                 \
    for (int ni = 0; ni < 4; ++ni)                                    \
      bfv[ni] = *(const sv8*)&Bs[bp][bco + ni * 1024 + sB1];          \
    __builtin_amdgcn_s_barrier();       /* B1: all kh1 reads done */  \
    if ((kt) < 46) { A_ISSUE(bp, 0, (kt) + 2) A_ISSUE(bp, 1, (kt) + 2) } \
    asm volatile("s_waitcnt lgkmcnt(0)" ::: "memory");                \
    MFMA16                                                            \
    if ((kt) < 46)       { asm volatile("s_waitcnt vmcnt(8)" ::: "memory"); } \
    else if ((kt) == 46) { asm volatile("s_waitcnt vmcnt(0)" ::: "memory"); } \
    __builtin_amdgcn_s_barrier(); }

  // ---- prologue: A(0), B(0), A(1) in flight; retire tile 0; keep A(1) ----
  A_ISSUE(0, 0, 0) A_ISSUE(0, 1, 0)
  B_ISSUE(0, 0)
  A_ISSUE(1, 0, 1) A_ISSUE(1, 1, 1)
  asm volatile("s_waitcnt vmcnt(8)" ::: "memory");
  __builtin_amdgcn_s_barrier();

  // ---- main loop: 48 K-tiles, 2 phases each ----
  for (int tt = 0; tt < 24; ++tt) {
    const int kt = tt * 2;
    PH1(kt, 0) PH2(kt, 0)
    PH1(kt + 1, 1) PH2(kt + 1, 1)
  }

  // ---- epilogue: p[row] += sum_{cols in tile} tanh(acc + hb) * w2 ----
  // C layout: col = lane&15 (N), row = (lane>>4)*4 + j (M)
  const int b = row0 >> 10;
  float w2v[4], hbv[4];
#pragma unroll
  for (int ni = 0; ni < 4; ++ni) {
    int c = col0 + wn * 64 + ni * 16 + r15;
    w2v[ni] = w2[c];
    hbv[ni] = hb[(b << 10) + c];
  }
#pragma unroll
  for (int mi = 0; mi < 4; ++mi) {
#pragma unroll
    for (int j = 0; j < 4; ++j) {
      float pz = 0.f;
#pragma unroll
      for (int ni = 0; ni < 4; ++ni)
        pz += tanhf(acc[mi][ni][j] + hbv[ni]) * w2v[ni];
      pz += __shfl_xor(pz, 1); pz += __shfl_xor(pz, 2);
      pz += __shfl_xor(pz, 4); pz += __shfl_xor(pz, 8);
      if (r15 == 0) {
        int row = row0 + wm * 64 + mi * 16 + (qv << 2) + j;
        pe[(row << 4) + (ntile << 1) + wn] = pz;   // 16 slots/row
      }
    }
  }
#undef A_ISSUE
#undef B_ISSUE
#undef MFMA16
#undef PH1
#undef PH2
}

// ---------------- kernel 4: softmax over S per batch ----------------
__global__ void softmax_kernel(const float* __restrict__ pe, float* __restrict__ alpha) {
  int b = blockIdx.x, t = threadIdx.x;
  int lane = t & 63, wid = t >> 6;
  float ev[4];
#pragma unroll
  for (int r = 0; r < 4; ++r) {
    int s = t + r * 256;
    const float* p = pe + ((b << 10) + s) * 16;
    float sum = 0.f;
#pragma unroll
    for (int i = 0; i < 16; ++i) sum += p[i];
    ev[r] = sum;
  }
  float m = fmaxf(fmaxf(ev[0], ev[1]), fmaxf(ev[2], ev[3]));
#pragma unroll
  for (int off = 32; off; off >>= 1) m = fmaxf(m, __shfl_xor(m, off));
  __shared__ float red[8];
  if (lane == 0) red[wid] = m;
  __syncthreads();
  m = fmaxf(fmaxf(red[0], red[1]), fmaxf(red[2], red[3]));
  float p4[4], ls = 0.f;
#pragma unroll
  for (int r = 0; r < 4; ++r) { p4[r] = expf(ev[r] - m); ls += p4[r]; }
#pragma unroll
  for (int off = 32; off; off >>= 1) ls += __shfl_xor(ls, off);
  if (lane == 0) red[4 + wid] = ls;
  __syncthreads();
  float inv = 1.0f / (red[4] + red[5] + red[6] + red[7]);
#pragma unroll
  for (int r = 0; r < 4; ++r) alpha[(b << 10) + t + r * 256] = p4[r] * inv;
}

// ---------------- kernel 5: context partials over s-chunks ----------------
__global__ void ctxpart_kernel(const float* __restrict__ enc, const float* __restrict__ alpha,
                               float* __restrict__ part) {
  int bid = blockIdx.x, b = bid >> 4, sc = bid & 15;
  int t = threadIdx.x;
  __shared__ float sal[64];
  if (t < 64) sal[t] = alpha[(b << 10) + (sc << 6) + t];
  __syncthreads();
  const fx4* ev = (const fx4*)enc;
  fx4 a0 = {}, a1 = {}, a2 = {};
  int base = ((b << 10) + (sc << 6)) * 768;
  for (int si = 0; si < 64; ++si) {
    float a = sal[si];
    const fx4* rp = ev + base + si * 768;
    a0 += a * rp[t];
    a1 += a * rp[256 + t];
    a2 += a * rp[512 + t];
  }
  fx4* pp = (fx4*)part;
  int pb = ((b << 4) + sc) * 768;
  pp[pb + t] = a0; pp[pb + 256 + t] = a1; pp[pb + 512 + t] = a2;
}

__global__ void ctxreduce_kernel(const float* __restrict__ part, float* __restrict__ ctx) {
  int j = blockIdx.x * 256 + threadIdx.x;     // 0..24575 fx4
  int b = j / 768, fi = j - b * 768;
  const fx4* pp = (const fx4*)part;
  fx4 s = {};
#pragma unroll
  for (int i = 0; i < 16; ++i) s += pp[((b << 4) + i) * 768 + fi];
  ((fx4*)ctx)[b * 768 + fi] = s;
}

// ---------------- kernel 6: out = ctx·W3^T + b3 ----------------
__global__ void final_kernel(const float* __restrict__ ctx, const float* __restrict__ W3,
                             const float* __restrict__ b3, float* __restrict__ out) {
  int idx = (blockIdx.x << 2) + (threadIdx.x >> 6);   // b*1024 + d
  int lane = threadIdx.x & 63;
  int b = idx >> 10, d = idx & 1023;
  const fx4* cv = (const fx4*)ctx;
  const fx4* wv = (const fx4*)W3;
  float s = 0.f;
#pragma unroll
  for (int i = 0; i < 12; ++i) {
    int f4 = lane + (i << 6);
    fx4 c = cv[b * 768 + f4];
    fx4 w = wv[d * 768 + f4];
    s += c[0] * w[0] + c[1] * w[1] + c[2] * w[2] + c[3] * w[3];
  }
#pragma unroll
  for (int off = 32; off; off >>= 1) s += __shfl_xor(s, off);
  if (lane == 0) out[idx] = s + b3[d];
}

extern "C" void kernel_launch(void* const* d_in, const int* in_sizes, int n_in,
                              void* d_out, int out_size, void* d_ws, size_t ws_size,
                              hipStream_t stream) {
  const float* hs  = (const float*)d_in[0];   // (32, 1024)
  const float* enc = (const float*)d_in[1];   // (32, 1024, 3072)
  const float* W1  = (const float*)d_in[2];   // (1024, 4096)
  const float* b1  = (const float*)d_in[3];   // (1024)
  const float* w2  = (const float*)d_in[4];   // (1, 1024)
  const float* W3  = (const float*)d_in[5];   // (1024, 3072)
  const float* b3  = (const float*)d_in[6];   // (1024)
  float* out = (float*)d_out;

  char* ws = (char*)d_ws;                     // ~15.3 MB used, write-before-read
  unsigned short* W1a = (unsigned short*)(ws);          // 6,291,456 B
  float* pe    = (float*)(ws + 6291456);                // 2,097,152 B
  float* alpha = (float*)(ws + 8388608);                // 131,072 B
  float* hb    = (float*)(ws + 8519680);                // 131,072 B
  float* ctx   = (float*)(ws + 8650752);                // 393,216 B
  float* part  = (float*)(ws + 9043968);                // 6,291,456 B

  convw1_kernel<<<3072, 256, 0, stream>>>(W1, W1a);
  hbias_kernel<<<8192, 256, 0, stream>>>(hs, W1, b1, hb);
  gemm_score<<<1024, 512, 0, stream>>>(enc, W1a, hb, w2, pe);
  softmax_kernel<<<32, 256, 0, stream>>>(pe, alpha);
  ctxpart_kernel<<<512, 256, 0, stream>>>(enc, alpha, part);
  ctxreduce_kernel<<<96, 256, 0, stream>>>(part, ctx);
  final_kernel<<<8192, 256, 0, stream>>>(ctx, W3, b3, out);
}

// Round 9
// 415.678 us; speedup vs baseline: 1.2965x; 1.2965x over previous
//
#include <hip/hip_runtime.h>
#include <hip/hip_bf16.h>

// Attention_aux: fused aux-attention scorer + context + output projection.
//   1. convw1:   W1[:, :3072] -> bf16 (ws)
//   2. hbias:    hb[b,d] = hs[b,:]·W1[d,3072:] + b1[d]  (fp32)
//   3. gemm_score: bf16 MFMA  pre = enc·W1a^T ; epilogue p = sum tanh(pre+hb)*w2
//      R4 structure (best measured: 360us) + fixes:
//      256x256 tile, BK=32, 8 waves (2Mx4N, wave 128x64, acc 8x4), dbuf,
//      counted vmcnt, 2 raw barriers/iter.
//      FIX1: A LDS rows padded to 40 elems (80B) -> conflict-free frag reads
//            (A is reg-staged so padding is legal; no XOR swizzle needed).
//      FIX2: B LDS as [128 ldsrows x 128B] (2 cols/row) + 8-slot XOR swizzle
//            (R6-verified 0-conflict geometry), gload_lds linear dest,
//            pre-unswizzled per-lane source (rule 21 both-sides).
//      FIX3: A prefetch depth 2 (pa[2][4], 2-iter ~600cy window covers HBM).
//   4. softmax over S -> alpha
//   5. ctxpart/ctxreduce: context = alpha^T · enc  (fp32, deterministic)
//   6. final:    out = context·W3^T + b3

typedef float          fx4 __attribute__((ext_vector_type(4)));
typedef short          sv8 __attribute__((ext_vector_type(8)));
typedef unsigned short uv4 __attribute__((ext_vector_type(4)));
typedef unsigned int   ui4 __attribute__((ext_vector_type(4)));

__device__ __forceinline__ unsigned short f2bf(float x) {
  unsigned u = __float_as_uint(x);
  return (unsigned short)((u + 0x7FFFu + ((u >> 16) & 1u)) >> 16);
}

// packed RNE f32x2 -> bf16x2 via HW instruction
__device__ __forceinline__ unsigned cvtpk(float lo, float hi) {
  unsigned r;
  asm("v_cvt_pk_bf16_f32 %0, %1, %2" : "=v"(r) : "v"(lo), "v"(hi));
  return r;
}
__device__ __forceinline__ ui4 pack8(fx4 a, fx4 b) {
  ui4 v;
  v[0] = cvtpk(a[0], a[1]); v[1] = cvtpk(a[2], a[3]);
  v[2] = cvtpk(b[0], b[1]); v[3] = cvtpk(b[2], b[3]);
  return v;
}

// ---------------- kernel 1: convert W1[:, :3072] to bf16 ----------------
__global__ void convw1_kernel(const float* __restrict__ W1, unsigned short* __restrict__ W1a) {
  int id = blockIdx.x * 256 + threadIdx.x;      // float4 id, 1024*768 total
  int d = id / 768, fi = id - d * 768;
  fx4 v = ((const fx4*)W1)[d * 1024 + fi];
  uv4 r; r[0] = f2bf(v[0]); r[1] = f2bf(v[1]); r[2] = f2bf(v[2]); r[3] = f2bf(v[3]);
  ((uv4*)W1a)[d * 768 + fi] = r;
}

// ---------------- kernel 2: hidden-state bias  hb[b,d] ----------------
__global__ void hbias_kernel(const float* __restrict__ hs, const float* __restrict__ W1,
                             const float* __restrict__ b1, float* __restrict__ hb) {
  int idx = (blockIdx.x << 2) + (threadIdx.x >> 6);   // 0..32767 = b*1024+d
  int lane = threadIdx.x & 63;
  int b = idx >> 10, d = idx & 1023;
  const fx4* hv = (const fx4*)hs;
  const fx4* wv = (const fx4*)W1;
  float s = 0.f;
#pragma unroll
  for (int i = 0; i < 4; ++i) {
    int k4 = lane + (i << 6);
    fx4 h = hv[(b << 8) + k4];
    fx4 w = wv[d * 1024 + 768 + k4];
    s += h[0] * w[0] + h[1] * w[1] + h[2] * w[2] + h[3] * w[3];
  }
#pragma unroll
  for (int off = 32; off; off >>= 1) s += __shfl_xor(s, off);
  if (lane == 0) hb[idx] = s + b1[d];
}

// ---------------- kernel 3: big GEMM + tanh·w2 epilogue ----------------
// M=32768, N=1024, K=3072. Block 256x256, BK=32, 96 iters, 8 waves (2Mx4N),
// wave 128x64 (acc 8x4 = 32 MFMA/iter). Per-iter: COMPUTE(p); A_WRITE(kt+1);
// A_LOAD(kt+3); bar; B_ISSUE(kt+2 into buf p); vmcnt(6); lgkm0; bar.
// Steady in-flight after vmcnt(6): A(kt+3):4 + B(kt+2):2. Hand-verified FIFO.
__global__ __launch_bounds__(512, 2)
void gemm_score(const float* __restrict__ enc,
                const unsigned short* __restrict__ W1a,
                const float* __restrict__ hb,
                const float* __restrict__ w2,
                float* __restrict__ pe) {
  __shared__ __align__(16) unsigned short As[2][10240];  // [256 rows][40] pad
  __shared__ __align__(16) unsigned short Bs[2][8192];   // [128 ldsrows][64]

  const int t = threadIdx.x;
  const int lane = t & 63, wid = t >> 6;
  const int wm = wid >> 2, wn = wid & 3;          // 2M x 4N wave grid

  // XCD-bijective swizzle: 512 blocks, XCD x owns lg [x*64, x*64+64)
  const int bid = blockIdx.x;
  const int lg = ((bid & 7) << 6) | (bid >> 3);
  const int mt = lg >> 2, ntile = lg & 3;
  const int row0 = mt << 8;            // 256-row M tile
  const int col0 = ntile << 8;         // 256-col N tile

  const fx4* encv = (const fx4*)enc;   // enc row = 768 fx4

  // ---- A staging: thread t -> row t>>1, k-half (t&1)*16 floats ----
  const int ar = t >> 1, ah = t & 1;
  const int agb = (row0 + ar) * 768 + ah * 4;     // fx4 index; + kt*8
  const int awb = ar * 40 + ah * 16;              // padded row stride 40

  // ---- B staging: 2 gload_lds/thread, 128B LDS rows (2 cols each) ----
  // lds-row R = wid*16 + i*8 + (l>>3), stored slot S = l&7 (linear dest).
  // unswizzle: pre = S ^ (R&7) = (l&7)^(l>>3); col = 2R + (pre>>2); k-slot pre&3.
  const int l3 = lane >> 3, l7 = lane & 7;
  const int pre = l7 ^ l3;
  const unsigned short* bsrc0 =
      W1a + (size_t)(col0 + wid * 32 + 2 * l3 + (pre >> 2)) * 3072 + (pre & 3) * 8;
  const unsigned short* bsrc1 = bsrc0 + (size_t)16 * 3072;
  const int bdst0 = (wid * 16) * 64;
  const int bdst1 = (wid * 16 + 8) * 64;

  // ---- fragment read offsets ----
  const int r15 = lane & 15, qv = lane >> 4;
  const int aro = (wm * 128 + r15) * 40 + qv * 8;       // + mi*640
  const int cb = wn * 64 + r15;                          // global col within tile
  const int bro = (cb >> 1) * 64 + (((((cb & 1) << 2) + qv) ^ ((cb >> 1) & 7)) << 3); // + ni*512

  fx4 acc[8][4] = {};
  fx4 pa[2][4];

#define A_LOAD(s, kt) { _Pragma("unroll") for (int j = 0; j < 4; ++j) pa[s][j] = encv[agb + (kt) * 8 + j]; }
#define A_WRITE(s, buf) { *(ui4*)&As[buf][awb] = pack8(pa[s][0], pa[s][1]); \
                          *(ui4*)&As[buf][awb + 8] = pack8(pa[s][2], pa[s][3]); }
#define B_ISSUE(buf, kt)                                              \
  { __builtin_amdgcn_global_load_lds(                                 \
        (const __attribute__((address_space(1))) void*)(bsrc0 + (kt) * 32), \
        (__attribute__((address_space(3))) void*)&Bs[buf][bdst0], 16, 0, 0); \
    __builtin_amdgcn_global_load_lds(                                 \
        (const __attribute__((address_space(1))) void*)(bsrc1 + (kt) * 32), \
        (__attribute__((address_space(3))) void*)&Bs[buf][bdst1], 16, 0, 0); }
#define COMPUTE(p)                                                    \
  { sv8 af[8], bfv[4];                                                \
    _Pragma("unroll")                                                 \
    for (int mi = 0; mi < 8; ++mi) af[mi] = *(const sv8*)&As[p][aro + mi * 640]; \
    _Pragma("unroll")                                                 \
    for (int ni = 0; ni < 4; ++ni) bfv[ni] = *(const sv8*)&Bs[p][bro + ni * 512]; \
    _Pragma("unroll")                                                 \
    for (int mi = 0; mi < 8; ++mi)                                    \
      _Pragma("unroll")                                               \
      for (int ni = 0; ni < 4; ++ni)                                  \
        acc[mi][ni] = __builtin_amdgcn_mfma_f32_16x16x32_bf16(af[mi], bfv[ni], acc[mi][ni], 0, 0, 0); }
#define ITER(kt, p)                                                   \
  { COMPUTE(p)                                                        \
    if ((kt) < 95) { A_WRITE(p ^ 1, p ^ 1) }   /* A(kt+1) -> As[p^1] */ \
    if ((kt) < 93) { A_LOAD(p ^ 1, (kt) + 3) } /* refill freed slot */  \
    __builtin_amdgcn_s_barrier();              /* Bs[p] reads done  */  \
    if ((kt) < 94) {                                                  \
      B_ISSUE(p, (kt) + 2)                                            \
      asm volatile("s_waitcnt vmcnt(6)" ::: "memory");                \
    } else if ((kt) == 94) {                                          \
      asm volatile("s_waitcnt vmcnt(0)" ::: "memory");                \
    }                                                                 \
    asm volatile("s_waitcnt lgkmcnt(0)" ::: "memory");                \
    __builtin_amdgcn_s_barrier(); }            /* tile kt+1 ready */

  // ---- prologue ----
  A_LOAD(0, 0)
  A_LOAD(1, 1)
  B_ISSUE(0, 0)
  A_WRITE(0, 0)              // waits pa[0] loads (A(1),B(0) stay in flight)
  B_ISSUE(1, 1)
  A_LOAD(0, 2)
  asm volatile("s_waitcnt vmcnt(6)" ::: "memory");   // retires A(1),B(0)
  asm volatile("s_waitcnt lgkmcnt(0)" ::: "memory");
  __builtin_amdgcn_s_barrier();

  // ---- main loop: 96 K-tiles ----
  for (int kt2 = 0; kt2 < 48; ++kt2) {
    const int kt = kt2 * 2;
    ITER(kt, 0)
    ITER(kt + 1, 1)
  }

  // ---- epilogue: p[row] += sum_{cols in tile} tanh(acc + hb) * w2 ----
  // C layout: col = lane&15 (N), row = (lane>>4)*4 + j (M)
  const int b = row0 >> 10;
  float w2v[4], hbv[4];
#pragma unroll
  for (int ni = 0; ni < 4; ++ni) {
    int c = col0 + wn * 64 + ni * 16 + r15;
    w2v[ni] = w2[c];
    hbv[ni] = hb[(b << 10) + c];
  }
#pragma unroll
  for (int mi = 0; mi < 8; ++mi) {
#pragma unroll
    for (int j = 0; j < 4; ++j) {
      float pz = 0.f;
#pragma unroll
      for (int ni = 0; ni < 4; ++ni)
        pz += tanhf(acc[mi][ni][j] + hbv[ni]) * w2v[ni];
      pz += __shfl_xor(pz, 1); pz += __shfl_xor(pz, 2);
      pz += __shfl_xor(pz, 4); pz += __shfl_xor(pz, 8);
      if (r15 == 0) {
        int row = row0 + wm * 128 + mi * 16 + (qv << 2) + j;
        pe[(row << 4) + (ntile << 2) + wn] = pz;   // 16 slots/row
      }
    }
  }
#undef A_LOAD
#undef A_WRITE
#undef B_ISSUE
#undef COMPUTE
#undef ITER
}

// ---------------- kernel 4: softmax over S per batch ----------------
__global__ void softmax_kernel(const float* __restrict__ pe, float* __restrict__ alpha) {
  int b = blockIdx.x, t = threadIdx.x;
  int lane = t & 63, wid = t >> 6;
  float ev[4];
#pragma unroll
  for (int r = 0; r < 4; ++r) {
    int s = t + r * 256;
    const float* p = pe + ((b << 10) + s) * 16;
    float sum = 0.f;
#pragma unroll
    for (int i = 0; i < 16; ++i) sum += p[i];
    ev[r] = sum;
  }
  float m = fmaxf(fmaxf(ev[0], ev[1]), fmaxf(ev[2], ev[3]));
#pragma unroll
  for (int off = 32; off; off >>= 1) m = fmaxf(m, __shfl_xor(m, off));
  __shared__ float red[8];
  if (lane == 0) red[wid] = m;
  __syncthreads();
  m = fmaxf(fmaxf(red[0], red[1]), fmaxf(red[2], red[3]));
  float p4[4], ls = 0.f;
#pragma unroll
  for (int r = 0; r < 4; ++r) { p4[r] = expf(ev[r] - m); ls += p4[r]; }
#pragma unroll
  for (int off = 32; off; off >>= 1) ls += __shfl_xor(ls, off);
  if (lane == 0) red[4 + wid] = ls;
  __syncthreads();
  float inv = 1.0f / (red[4] + red[5] + red[6] + red[7]);
#pragma unroll
  for (int r = 0; r < 4; ++r) alpha[(b << 10) + t + r * 256] = p4[r] * inv;
}

// ---------------- kernel 5: context partials over s-chunks ----------------
__global__ void ctxpart_kernel(const float* __restrict__ enc, const float* __restrict__ alpha,
                               float* __restrict__ part) {
  int bid = blockIdx.x, b = bid >> 4, sc = bid & 15;
  int t = threadIdx.x;
  __shared__ float sal[64];
  if (t < 64) sal[t] = alpha[(b << 10) + (sc << 6) + t];
  __syncthreads();
  const fx4* ev = (const fx4*)enc;
  fx4 a0 = {}, a1 = {}, a2 = {};
  int base = ((b << 10) + (sc << 6)) * 768;
  for (int si = 0; si < 64; ++si) {
    float a = sal[si];
    const fx4* rp = ev + base + si * 768;
    a0 += a * rp[t];
    a1 += a * rp[256 + t];
    a2 += a * rp[512 + t];
  }
  fx4* pp = (fx4*)part;
  int pb = ((b << 4) + sc) * 768;
  pp[pb + t] = a0; pp[pb + 256 + t] = a1; pp[pb + 512 + t] = a2;
}

__global__ void ctxreduce_kernel(const float* __restrict__ part, float* __restrict__ ctx) {
  int j = blockIdx.x * 256 + threadIdx.x;     // 0..24575 fx4
  int b = j / 768, fi = j - b * 768;
  const fx4* pp = (const fx4*)part;
  fx4 s = {};
#pragma unroll
  for (int i = 0; i < 16; ++i) s += pp[((b << 4) + i) * 768 + fi];
  ((fx4*)ctx)[b * 768 + fi] = s;
}

// ---------------- kernel 6: out = ctx·W3^T + b3 ----------------
__global__ void final_kernel(const float* __restrict__ ctx, const float* __restrict__ W3,
                             const float* __restrict__ b3, float* __restrict__ out) {
  int idx = (blockIdx.x << 2) + (threadIdx.x >> 6);   // b*1024 + d
  int lane = threadIdx.x & 63;
  int b = idx >> 10, d = idx & 1023;
  const fx4* cv = (const fx4*)ctx;
  const fx4* wv = (const fx4*)W3;
  float s = 0.f;
#pragma unroll
  for (int i = 0; i < 12; ++i) {
    int f4 = lane + (i << 6);
    fx4 c = cv[b * 768 + f4];
    fx4 w = wv[d * 768 + f4];
    s += c[0] * w[0] + c[1] * w[1] + c[2] * w[2] + c[3] * w[3];
  }
#pragma unroll
  for (int off = 32; off; off >>= 1) s += __shfl_xor(s, off);
  if (lane == 0) out[idx] = s + b3[d];
}

extern "C" void kernel_launch(void* const* d_in, const int* in_sizes, int n_in,
                              void* d_out, int out_size, void* d_ws, size_t ws_size,
                              hipStream_t stream) {
  const float* hs  = (const float*)d_in[0];   // (32, 1024)
  const float* enc = (const float*)d_in[1];   // (32, 1024, 3072)
  const float* W1  = (const float*)d_in[2];   // (1024, 4096)
  const float* b1  = (const float*)d_in[3];   // (1024)
  const float* w2  = (const float*)d_in[4];   // (1, 1024)
  const float* W3  = (const float*)d_in[5];   // (1024, 3072)
  const float* b3  = (const float*)d_in[6];   // (1024)
  float* out = (float*)d_out;

  char* ws = (char*)d_ws;                     // ~15.3 MB used, write-before-read
  unsigned short* W1a = (unsigned short*)(ws);          // 6,291,456 B
  float* pe    = (float*)(ws + 6291456);                // 2,097,152 B
  float* alpha = (float*)(ws + 8388608);                // 131,072 B
  float* hb    = (float*)(ws + 8519680);                // 131,072 B
  float* ctx   = (float*)(ws + 8650752);                // 393,216 B
  float* part  = (float*)(ws + 9043968);                // 6,291,456 B

  convw1_kernel<<<3072, 256, 0, stream>>>(W1, W1a);
  hbias_kernel<<<8192, 256, 0, stream>>>(hs, W1, b1, hb);
  gemm_score<<<512, 512, 0, stream>>>(enc, W1a, hb, w2, pe);
  softmax_kernel<<<32, 256, 0, stream>>>(pe, alpha);
  ctxpart_kernel<<<512, 256, 0, stream>>>(enc, alpha, part);
  ctxreduce_kernel<<<96, 256, 0, stream>>>(part, ctx);
  final_kernel<<<8192, 256, 0, stream>>>(ctx, W3, b3, out);
}